// Round 10
// baseline (665.920 us; speedup 1.0000x reference)
//
#include <hip/hip_runtime.h>

#define T_DATA 200000
#define E_NO 400
#define I_NO 100
#define SUB_NO 20
#define N_BASIS 20
#define T_NO 200

typedef unsigned short u16;
typedef unsigned int u32;

// ---- workspace layout ----
#define WS_K4    0                       // 4000 float4 = 64000
#define WS_HIST2 64000                   // 200 float2
#define WS_LISTS 65600                   // 542 int -> end 67768
#define WS_SYNE  131072                  // 20*200000 u16 = 8e6
#define WS_SYNI  (WS_SYNE + 8000000)
#define WS_SNS   (WS_SYNI + 8000000)
#define WS_SS    (WS_SNS + 8000000)
#define WS_HF    (WS_SS + 8000000)       // 200000 float2 = 1.6e6
#define WS_NEED  (WS_HF + 1600000)       // ~33.7 MB (ws_size ~1.28 GB per R9)

__device__ __forceinline__ u16 f2bf(float f) {
    union { float f; u32 u; } v; v.f = f;
    u32 u = v.u;
    u32 lsb = (u >> 16) & 1u;
    u += 0x7fffu + lsb;            // RNE
    return (u16)(u >> 16);
}
__device__ __forceinline__ float bf2f(u16 b) {
    union { u32 u; float f; } v; v.u = ((u32)b) << 16; return v.f;
}
__device__ __forceinline__ void unpack8(uint4 u, float* x) {
    union { u32 u; float f; } c;
    c.u = u.x << 16;          x[0] = c.f;
    c.u = u.x & 0xffff0000u;  x[1] = c.f;
    c.u = u.y << 16;          x[2] = c.f;
    c.u = u.y & 0xffff0000u;  x[3] = c.f;
    c.u = u.z << 16;          x[4] = c.f;
    c.u = u.z & 0xffff0000u;  x[5] = c.f;
    c.u = u.w << 16;          x[6] = c.f;
    c.u = u.w & 0xffff0000u;  x[7] = c.f;
}
__device__ __forceinline__ float fast_tanh(float x) {
    x = fminf(fmaxf(x, -15.f), 15.f);
    float e = __expf(2.f * x);
    return 1.f - 2.f / (e + 1.f);
}
__device__ __forceinline__ float fast_sigmoid(float x) {
    x = fminf(fmaxf(x, -30.f), 30.f);
    return 1.f / (1.f + __expf(-x));
}

// ============================================================================
// k_setup: 22 blocks. 0..19 subunit filters -> k4/outF; 20 hist kernels;
// 21 assignment lists.
// ============================================================================
__global__ __launch_bounds__(256) void k_setup(
    const float* __restrict__ Wns, const float* __restrict__ Tau,
    const float* __restrict__ Del, const float* __restrict__ Wsyns,
    const float* __restrict__ HwS, const float* __restrict__ HwNS,
    const float* __restrict__ Cse, const float* __restrict__ Csi,
    float4* __restrict__ k4, float2* __restrict__ hist2,
    int* __restrict__ lists, float* __restrict__ outF)
{
    __shared__ float cb[N_BASIS * T_NO];
    __shared__ int easn[E_NO], iasn[I_NO];
    __shared__ int cnt[2 * SUB_NO], cur[2 * SUB_NO];
    const int tid = threadIdx.x;
    const int b = blockIdx.x;
    const float PI = 3.14159265358979323846f;

    if (b == 21) {
        // ---- assignment lists ----
        if (tid < 2 * SUB_NO) cnt[tid] = 0;
        __syncthreads();
        for (int j = tid; j < E_NO; j += 256) {
            int a = 0;
            for (int s = 0; s < SUB_NO; ++s)
                if (Cse[s * E_NO + j] > 0.5f) a = s;
            easn[j] = a;
            atomicAdd(&cnt[a], 1);
        }
        for (int j = tid; j < I_NO; j += 256) {
            int a = 0;
            for (int s = 0; s < SUB_NO; ++s)
                if (Csi[s * I_NO + j] > 0.5f) a = s;
            iasn[j] = a;
            atomicAdd(&cnt[SUB_NO + a], 1);
        }
        __syncthreads();
        if (tid == 0) {
            int aE = 0, aI = 0;
            for (int s = 0; s < SUB_NO; ++s) {
                lists[s] = aE;      cur[s] = aE;           aE += cnt[s];
                lists[21 + s] = aI; cur[SUB_NO + s] = aI;  aI += cnt[SUB_NO + s];
            }
            lists[20] = aE;
            lists[41] = aI;
        }
        __syncthreads();
        for (int j = tid; j < E_NO; j += 256) {
            int p = atomicAdd(&cur[easn[j]], 1);
            lists[42 + p] = j;
        }
        for (int j = tid; j < I_NO; j += 256) {
            int p = atomicAdd(&cur[SUB_NO + iasn[j]], 1);
            lists[442 + p] = j;
        }
        return;
    }

    for (int it = tid; it < N_BASIS * T_NO; it += 256) {
        int bb = it / T_NO, j = it - bb * T_NO;
        float phi = 1.57079632679489662f * (float)bb;
        float raw = 5.0f * logf((float)j + 1.0f);
        float v = 0.f;
        if (raw >= phi - PI && raw <= phi + PI) v = 0.5f * cosf(raw - phi) + 0.5f;
        cb[it] = v;
    }
    __syncthreads();

    if (b < 20) {
        const int s = b;
        if (tid < T_NO) {
            const int j = tid;
            float tau_e = Tau[s * 2 + 0]; tau_e *= tau_e;
            float tau_i = Tau[s * 2 + 1]; tau_i *= tau_i;
            float de = Del[s * 2 + 0], di = Del[s * 2 + 1];
            float we = Wns[s * 2 + 0]; we *= we;
            float wi = Wns[s * 2 + 1]; wi *= wi;
            float te = fmaxf((float)j - de, 0.f) / tau_e;
            float ti = fmaxf((float)j - di, 0.f) / tau_i;
            float eNs = te * expf(-te) * we;
            float iNs = -ti * expf(-ti) * wi;
            float eS = 0.f, iS = 0.f;
            for (int bb = 0; bb < N_BASIS; ++bb) {
                float w0 = Wsyns[(s * N_BASIS + bb) * 2 + 0];
                float w1 = Wsyns[(s * N_BASIS + bb) * 2 + 1];
                float c = cb[bb * T_NO + j];
                eS += w0 * w0 * c;
                iS -= w1 * w1 * c;
            }
            int it = s * T_NO + j;
            k4[it] = make_float4(eNs, iNs, eS, iS);
            outF[it]         = eNs;
            outF[4000 + it]  = iNs;
            outF[8000 + it]  = eS;
            outF[12000 + it] = iS;
        }
    } else {
        if (tid < T_NO) {
            const int j = tid;
            float hn = 0.f, hs = 0.f;
            for (int bb = 0; bb < N_BASIS; ++bb) {
                float c = cb[bb * T_NO + j];
                hn += HwNS[bb] * c;
                hs += HwS[bb] * c;
            }
            hist2[j] = make_float2(hn, hs);
            outF[16000 + j] = hn;
            outF[16200 + j] = hs;
        }
    }
}

// ============================================================================
// k_spikes: spike sums -> bf16 synEb/synIb. 16 t per block, 34 KB LDS.
// ============================================================================
#define AR 16
__global__ __launch_bounds__(256) void k_spikes(
    const float* __restrict__ Se, const float* __restrict__ Si,
    const int* __restrict__ listsg,
    u16* __restrict__ synEb, u16* __restrict__ synIb)
{
    __shared__ __align__(16) float tE[AR * 404];
    __shared__ __align__(16) float tI[AR * 104];
    __shared__ int leo[21], lio[21];
    __shared__ u16 lei[E_NO], lii[I_NO];
    const int tid = threadIdx.x;
    const int t0 = blockIdx.x * AR;

    if (tid < 21) { leo[tid] = listsg[tid]; lio[tid] = listsg[21 + tid]; }
    for (int k = tid; k < E_NO; k += 256) lei[k] = (u16)listsg[42 + k];
    for (int k = tid; k < I_NO; k += 256) lii[k] = (u16)listsg[442 + k];

    const float4* Se4 = (const float4*)(Se + (size_t)t0 * E_NO);
    const float4* Si4 = (const float4*)(Si + (size_t)t0 * I_NO);
    for (int k = tid; k < AR * 100; k += 256) {
        int r = k / 100, c = k - r * 100;
        ((float4*)tE)[r * 101 + c] = Se4[k];
    }
    for (int k = tid; k < AR * 25; k += 256) {
        int r = k / 25, c = k - r * 25;
        ((float4*)tI)[r * 26 + c] = Si4[k];
    }
    __syncthreads();

    for (int task = tid; task < AR * SUB_NO; task += 256) {
        int s = task >> 4, r = task & 15;
        int k0 = leo[s], k1 = leo[s + 1];
        const float* row = tE + r * 404;
        float a0 = 0.f, a1 = 0.f, a2 = 0.f, a3 = 0.f;
        int k = k0;
        for (; k + 4 <= k1; k += 4) {
            a0 += row[lei[k]];
            a1 += row[lei[k + 1]];
            a2 += row[lei[k + 2]];
            a3 += row[lei[k + 3]];
        }
        for (; k < k1; ++k) a0 += row[lei[k]];
        synEb[(size_t)s * T_DATA + t0 + r] = f2bf((a0 + a1) + (a2 + a3));
    }
    for (int task = tid; task < AR * SUB_NO; task += 256) {
        int s = task >> 4, r = task & 15;
        const float* row = tI + r * 104;
        float a = 0.f;
        for (int k = lio[s]; k < lio[s + 1]; ++k) a += row[lii[k]];
        synIb[(size_t)s * T_DATA + t0 + r] = f2bf(a);
    }
}

// ============================================================================
// k_conv: depthwise conv. blockIdx.y: 0..4 = 4 subunits each; 5 = hist-of-Z
// (hist[t] = conv(Z)[t-1], stored f32 to hfilt). 24 KB LDS -> 6 blocks/CU.
// ============================================================================
#define TT 512
#define WROW 712
__global__ __launch_bounds__(256) void k_conv(
    const u16* __restrict__ synEb, const u16* __restrict__ synIb,
    const float* __restrict__ Z,
    const float4* __restrict__ k4g, const float2* __restrict__ hist2g,
    u16* __restrict__ synNSb, u16* __restrict__ synSb,
    float2* __restrict__ hfilt)
{
    __shared__ __align__(16) u16 wE[4 * WROW];        // 5696 B
    __shared__ __align__(16) u16 wI[4 * WROW];        // 5696 B
    __shared__ __align__(16) float4 k4l[4 * T_NO];    // 12800 B
    const int tid = threadIdx.x;
    const int t0 = blockIdx.x * TT;
    const int g  = blockIdx.y;
    const int W0 = t0 - 200;

    if (g < 5) {
        for (int q = tid; q < 712; q += 256) {
            int arr = (q >= 356) ? 1 : 0;
            int qq = q - arr * 356;
            int row = qq / 89, c = qq - row * 89;
            int s = g * 4 + row;
            const u16* src = (arr ? synIb : synEb) + (size_t)s * T_DATA;
            u16* dst = (arr ? wI : wE) + row * WROW + c * 8;
            int gg = W0 + c * 8;
            if (gg >= 0 && gg + 8 <= T_DATA) {
                *(uint4*)dst = *(const uint4*)(src + gg);
            } else {
                for (int e = 0; e < 8; ++e) {
                    int t = gg + e;
                    dst[e] = (t >= 0 && t < T_DATA) ? src[t] : (u16)0;
                }
            }
        }
        for (int q = tid; q < 800; q += 256) {
            int su = q / 200, j = q - su * 200;
            k4l[q] = k4g[(g * 4 + su) * T_NO + j];
        }
    } else {
        // zero wI (356 uint4) and wE rows 1..3 (267 uint4 from index 89)
        for (int q = tid; q < 623; q += 256) {
            if (q < 356) ((uint4*)wI)[q] = make_uint4(0, 0, 0, 0);
            else         ((uint4*)wE)[q - 356 + 89] = make_uint4(0, 0, 0, 0);
        }
        // wE row0 <- bf16(Z window)
        for (int c = tid; c < 89; c += 256) {
            int gg = W0 + c * 8;
            u16 zb[8];
            for (int e = 0; e < 8; ++e) {
                int t = gg + e;
                zb[e] = (t >= 0 && t < T_DATA) ? f2bf(Z[t]) : (u16)0;
            }
            u32 w0 = (u32)zb[0] | ((u32)zb[1] << 16);
            u32 w1 = (u32)zb[2] | ((u32)zb[3] << 16);
            u32 w2 = (u32)zb[4] | ((u32)zb[5] << 16);
            u32 w3 = (u32)zb[6] | ((u32)zb[7] << 16);
            *(uint4*)(wE + c * 8) = make_uint4(w0, w1, w2, w3);
        }
        for (int q = tid; q < 800; q += 256) {
            int su = q / 200, j = q - su * 200;
            float4 v = make_float4(0.f, 0.f, 0.f, 0.f);
            if (su == 0) {
                float2 h = hist2g[j];
                v = make_float4(h.x, 0.f, h.y, 0.f);
            }
            k4l[q] = v;
        }
    }
    __syncthreads();

    const int wv = tid >> 6;
    const int slot = tid & 63;
    const int bT = slot * 8;
    const u16* rowE = wE + wv * WROW;
    const u16* rowI = wI + wv * WROW;

    float aN[8], aS2[8];
#pragma unroll
    for (int m = 0; m < 8; ++m) { aN[m] = 0.f; aS2[m] = 0.f; }

#pragma unroll 1
    for (int jj = 0; jj <= 192; jj += 8) {
        const int p = bT + 192 - jj;
        float xe[16], xi[16];
        uint4 eA = *(const uint4*)(rowE + p);
        uint4 eB = *(const uint4*)(rowE + p + 8);
        uint4 iA = *(const uint4*)(rowI + p);
        uint4 iB = *(const uint4*)(rowI + p + 8);
        unpack8(eA, xe); unpack8(eB, xe + 8);
        unpack8(iA, xi); unpack8(iB, xi + 8);
#pragma unroll
        for (int k = 0; k < 8; ++k) {
            float4 kk = k4l[wv * T_NO + jj + k];
#pragma unroll
            for (int m = 0; m < 8; ++m) {
                float e = xe[m + 8 - k];
                float ii = xi[m + 8 - k];
                aN[m]  = fmaf(e, kk.x, fmaf(ii, kk.y, aN[m]));
                aS2[m] = fmaf(e, kk.z, fmaf(ii, kk.w, aS2[m]));
            }
        }
    }

    if (g < 5) {
        const int s = g * 4 + wv;
        const int t = t0 + bT;
        u32 w0 = (u32)f2bf(aN[0]) | ((u32)f2bf(aN[1]) << 16);
        u32 w1 = (u32)f2bf(aN[2]) | ((u32)f2bf(aN[3]) << 16);
        u32 w2 = (u32)f2bf(aN[4]) | ((u32)f2bf(aN[5]) << 16);
        u32 w3 = (u32)f2bf(aN[6]) | ((u32)f2bf(aN[7]) << 16);
        u32 v0 = (u32)f2bf(aS2[0]) | ((u32)f2bf(aS2[1]) << 16);
        u32 v1 = (u32)f2bf(aS2[2]) | ((u32)f2bf(aS2[3]) << 16);
        u32 v2 = (u32)f2bf(aS2[4]) | ((u32)f2bf(aS2[5]) << 16);
        u32 v3 = (u32)f2bf(aS2[6]) | ((u32)f2bf(aS2[7]) << 16);
        if (t + 8 <= T_DATA) {
            *(uint4*)(synNSb + (size_t)s * T_DATA + t) = make_uint4(w0, w1, w2, w3);
            *(uint4*)(synSb  + (size_t)s * T_DATA + t) = make_uint4(v0, v1, v2, v3);
        } else if (t < T_DATA) {
            for (int m = 0; m < 8 && t + m < T_DATA; ++m) {
                synNSb[(size_t)s * T_DATA + t + m] = f2bf(aN[m]);
                synSb[(size_t)s * T_DATA + t + m] = f2bf(aS2[m]);
            }
        }
    } else if (wv == 0) {
        // hist[t] = conv(Z)[t-1] -> store at t+1
#pragma unroll
        for (int m = 0; m < 8; ++m) {
            int tt = t0 + bT + m + 1;
            if (tt < T_DATA) hfilt[tt] = make_float2(aN[m], aS2[m]);
        }
        if (blockIdx.x == 0 && tid == 0) hfilt[0] = make_float2(0.f, 0.f);
    }
}

// ============================================================================
// k_tree: tree recursion + f32 outputs (hist precomputed). 24 KB LDS.
// ============================================================================
#define CT 256
__global__ __launch_bounds__(256) void k_tree(
    const u16* __restrict__ synNSb, const u16* __restrict__ synSb,
    const float2* __restrict__ hfilt,
    const int* __restrict__ Cden,
    const float* __restrict__ WsubNS, const float* __restrict__ WsubS,
    const float* __restrict__ Vo, const float* __restrict__ ThNS,
    const float* __restrict__ ThS,
    float* __restrict__ outV, float* __restrict__ outZ)
{
    __shared__ __align__(16) u16 lNS[SUB_NO * CT];
    __shared__ __align__(16) u16 lS[SUB_NO * CT];
    __shared__ float AS[SUB_NO][SUB_NO], AN[SUB_NO][SUB_NO];
    __shared__ float ths[SUB_NO], thn[SUB_NO];
    __shared__ float wn20s, vos;
    const int tid = threadIdx.x;
    const int t0 = blockIdx.x * CT;

    for (int q = tid; q < 1280; q += 256) {
        int arr = (q >= 640) ? 1 : 0;
        int qq = q - arr * 640;
        int row = qq >> 5, c = qq & 31;
        const u16* src = (arr ? synSb : synNSb) + (size_t)row * T_DATA;
        u16* dst = (arr ? lS : lNS) + row * CT + c * 8;
        int gg = t0 + c * 8;
        if (gg + 8 <= T_DATA) {
            *(uint4*)dst = *(const uint4*)(src + gg);
        } else {
            for (int e = 0; e < 8; ++e) {
                int t = gg + e;
                dst[e] = (t < T_DATA) ? src[t] : (u16)0;
            }
        }
    }
    for (int k = tid; k < SUB_NO * SUB_NO; k += 256) {
        int idx = k / SUB_NO, c = k - idx * SUB_NO;
        float m = (float)Cden[k];
        float wsv = WsubS[c];
        float wnv = WsubNS[c];
        AS[idx][c] = m * wsv * wsv;
        AN[idx][c] = m * wnv * wnv;
    }
    if (tid < SUB_NO) { ths[tid] = ThS[tid]; thn[tid] = ThNS[tid]; }
    if (tid == 0) {
        float w = WsubNS[0];
        wn20s = w * w;
        vos = Vo[0];
    }
    __syncthreads();

    const int t = t0 + tid;
    float2 hf = make_float2(0.f, 0.f);
    if (t < T_DATA) hf = hfilt[t];

    float vs[SUB_NO], vn[SUB_NO];
#pragma unroll
    for (int c = 0; c < SUB_NO; ++c) { vs[c] = 0.f; vn[c] = 0.f; }
#pragma unroll
    for (int idx = SUB_NO - 1; idx >= 1; --idx) {
        float cs = 0.f, cn = 0.f;
#pragma unroll
        for (int c = 0; c < SUB_NO; ++c) {
            cs = fmaf(AS[idx][c], vs[c], cs);
            cn = fmaf(AN[idx][c], vn[c], cn);
        }
        float synS_v = bf2f(lS[idx * CT + tid]);
        float synN_v = bf2f(lNS[idx * CT + tid]);
        vs[idx] = fast_tanh(synS_v + cs + ths[idx]);
        vn[idx] = fast_tanh(synN_v + cn + thn[idx]);
    }
    float cs0 = 0.f, cn0 = 0.f;
#pragma unroll
    for (int c = 0; c < SUB_NO; ++c) {
        cs0 = fmaf(AS[0][c], vs[c], cs0);
        cn0 = fmaf(AN[0][c], vn[c], cn0);
    }
    float s0  = fast_sigmoid(hf.y + bf2f(lS[tid]) + cs0 + ths[0]);
    float ns0 = fast_tanh(hf.x + bf2f(lNS[tid]) + cn0 + thn[0]);

    if (t < T_DATA) {
        outV[t] = ns0 * wn20s + vos;
        outZ[t] = s0;
    }
}

// ============================================================================
// k_fused (fallback only if ws too small — R8-proven)
// ============================================================================
__global__ __launch_bounds__(256) void k_fused(
    const float* __restrict__ Se, const float* __restrict__ Si,
    const float* __restrict__ Z,
    const float4* __restrict__ k4g, const float2* __restrict__ hist2g,
    const int* __restrict__ listsg,
    const int* __restrict__ Cden,
    const float* __restrict__ WsubNS, const float* __restrict__ WsubS,
    const float* __restrict__ Vo, const float* __restrict__ ThNS,
    const float* __restrict__ ThS,
    float* __restrict__ outV, float* __restrict__ outZ)
{
    __shared__ __align__(16) u16 sE[SUB_NO * WROW];
    __shared__ __align__(16) u16 sI[SUB_NO * WROW];
    __shared__ __align__(16) float scr[4032];
    __shared__ float AS[SUB_NO][SUB_NO], AN[SUB_NO][SUB_NO];
    __shared__ float ths[SUB_NO], thn[SUB_NO];
    __shared__ int leo[21], lio[21];
    __shared__ u16 lei[E_NO], lii[I_NO];
    __shared__ float wn20s, vos;
    const int tid = threadIdx.x;
    const int t0 = blockIdx.x * TT;
    const int W0 = t0 - 200;

    if (tid < 21) { leo[tid] = listsg[tid]; lio[tid] = listsg[21 + tid]; }
    for (int k = tid; k < E_NO; k += 256) lei[k] = (u16)listsg[42 + k];
    for (int k = tid; k < I_NO; k += 256) lii[k] = (u16)listsg[442 + k];
    for (int k = tid; k < SUB_NO * SUB_NO; k += 256) {
        int idx = k / SUB_NO, c = k - idx * SUB_NO;
        float m = (float)Cden[k];
        float wsv = WsubS[c];
        float wnv = WsubNS[c];
        AS[idx][c] = m * wsv * wsv;
        AN[idx][c] = m * wnv * wnv;
    }
    if (tid < SUB_NO) { ths[tid] = ThS[tid]; thn[tid] = ThNS[tid]; }
    if (tid == 0) {
        float w = WsubNS[0];
        wn20s = w * w;
        vos = Vo[0];
    }

    const float4* Se4 = (const float4*)Se;
    const float4* Si4 = (const float4*)Si;
    float4* scr4 = (float4*)scr;
    float4 pre[4];

#define LOAD_TILE(IT)                                                        \
    {                                                                        \
        _Pragma("unroll")                                                    \
        for (int q = 0; q < 4; ++q) {                                        \
            int k = tid + q * 256;                                           \
            float4 v = make_float4(0.f, 0.f, 0.f, 0.f);                      \
            if (k < 800) {                                                   \
                int r = k / 100, c = k - r * 100;                            \
                int t = W0 + (IT) * 8 + r;                                   \
                if (t >= 0 && t < T_DATA) v = Se4[t * 100 + c];              \
            } else if (k < 1000) {                                           \
                int kk = k - 800;                                            \
                int r = kk / 25, c = kk - r * 25;                            \
                int t = W0 + (IT) * 8 + r;                                   \
                if (t >= 0 && t < T_DATA) v = Si4[t * 25 + c];               \
            }                                                                \
            pre[q] = v;                                                      \
        }                                                                    \
    }

#define STORE_TILE()                                                         \
    {                                                                        \
        _Pragma("unroll")                                                    \
        for (int q = 0; q < 4; ++q) {                                        \
            int k = tid + q * 256;                                           \
            if (k < 800) {                                                   \
                scr4[k] = pre[q];                                            \
            } else if (k < 1000) {                                           \
                int kk = k - 800;                                            \
                int r = kk / 25, c = kk - r * 25;                            \
                scr4[800 + r * 26 + c] = pre[q];                             \
            }                                                                \
        }                                                                    \
    }

#define GATHER(IT)                                                           \
    {                                                                        \
        for (int task = tid; task < 320; task += 256) {                      \
            if (task < 160) {                                                \
                int r = task / 20, s = task - r * 20;                        \
                int k0 = leo[s], k1 = leo[s + 1];                            \
                const int bb = r * 400;                                      \
                float a0 = 0.f, a1 = 0.f, a2 = 0.f, a3 = 0.f;                \
                int k = k0;                                                  \
                for (; k + 4 <= k1; k += 4) {                                \
                    a0 += scr[bb + lei[k]];                                  \
                    a1 += scr[bb + lei[k + 1]];                              \
                    a2 += scr[bb + lei[k + 2]];                              \
                    a3 += scr[bb + lei[k + 3]];                              \
                }                                                            \
                for (; k < k1; ++k) a0 += scr[bb + lei[k]];                  \
                sE[s * WROW + (IT) * 8 + r] = f2bf((a0 + a1) + (a2 + a3));   \
            } else {                                                         \
                int tk = task - 160;                                         \
                int r = tk / 20, s = tk - r * 20;                            \
                int k0 = lio[s], k1 = lio[s + 1];                            \
                const int bb = 3200 + r * 104;                               \
                float a0 = 0.f;                                              \
                for (int k = k0; k < k1; ++k) a0 += scr[bb + lii[k]];        \
                sI[s * WROW + (IT) * 8 + r] = f2bf(a0);                      \
            }                                                                \
        }                                                                    \
    }

    LOAD_TILE(0);
    STORE_TILE();
    __syncthreads();
#pragma unroll 1
    for (int it = 1; it < 89; ++it) {
        LOAD_TILE(it);
        GATHER(it - 1);
        __syncthreads();
        STORE_TILE();
        __syncthreads();
    }
    GATHER(88);
    __syncthreads();

    for (int k = tid; k < WROW; k += 256) {
        int t = W0 + k;
        scr[k] = (t >= 0 && t < T_DATA) ? Z[t] : 0.f;
    }
    {
        float2* hl = (float2*)(scr + WROW);
        for (int k = tid; k < T_NO; k += 256) hl[k] = hist2g[k];
    }
    __syncthreads();
    float hn0 = 0.f, hs0 = 0.f, hn1 = 0.f, hs1 = 0.f;
    {
        const float2* hl = (const float2*)(scr + WROW);
        const int i0 = tid * 2;
        for (int j = 0; j < T_NO; ++j) {
            float2 h = hl[j];
            float za = scr[i0 + 199 - j];
            float zb = scr[i0 + 200 - j];
            hn0 = fmaf(h.x, za, hn0); hs0 = fmaf(h.y, za, hs0);
            hn1 = fmaf(h.x, zb, hn1); hs1 = fmaf(h.y, zb, hs1);
        }
    }
    __syncthreads();

    const int wv = tid >> 6;
    const int slot = tid & 63;
    const int bT = slot * 8;
    float4* k4c = (float4*)scr;

#pragma unroll 1
    for (int g = 0; g < 5; ++g) {
        for (int q = tid; q < 800; q += 256) {
            int su = q / 200, j = q - su * 200;
            k4c[q] = k4g[(g * 4 + su) * T_NO + j];
        }
        __syncthreads();

        const int s = g * 4 + wv;
        const u16* rowE = sE + s * WROW;
        const u16* rowI = sI + s * WROW;
        float aN[8], aS2[8];
#pragma unroll
        for (int m = 0; m < 8; ++m) { aN[m] = 0.f; aS2[m] = 0.f; }

#pragma unroll 1
        for (int jj = 0; jj <= 192; jj += 8) {
            const int p = bT + 192 - jj;
            float xe[16], xi[16];
            uint4 eA = *(const uint4*)(rowE + p);
            uint4 eB = *(const uint4*)(rowE + p + 8);
            uint4 iA = *(const uint4*)(rowI + p);
            uint4 iB = *(const uint4*)(rowI + p + 8);
            unpack8(eA, xe); unpack8(eB, xe + 8);
            unpack8(iA, xi); unpack8(iB, xi + 8);
#pragma unroll
            for (int k = 0; k < 8; ++k) {
                float4 kk = k4c[wv * 200 + jj + k];
#pragma unroll
                for (int m = 0; m < 8; ++m) {
                    float e = xe[m + 8 - k];
                    float ii = xi[m + 8 - k];
                    aN[m]  = fmaf(e, kk.x, fmaf(ii, kk.y, aN[m]));
                    aS2[m] = fmaf(e, kk.z, fmaf(ii, kk.w, aS2[m]));
                }
            }
        }
        __syncthreads();
        {
            u32 w0 = (u32)f2bf(aN[0]) | ((u32)f2bf(aN[1]) << 16);
            u32 w1 = (u32)f2bf(aN[2]) | ((u32)f2bf(aN[3]) << 16);
            u32 w2 = (u32)f2bf(aN[4]) | ((u32)f2bf(aN[5]) << 16);
            u32 w3 = (u32)f2bf(aN[6]) | ((u32)f2bf(aN[7]) << 16);
            *(uint4*)(sE + s * WROW + bT) = make_uint4(w0, w1, w2, w3);
            u32 v0 = (u32)f2bf(aS2[0]) | ((u32)f2bf(aS2[1]) << 16);
            u32 v1 = (u32)f2bf(aS2[2]) | ((u32)f2bf(aS2[3]) << 16);
            u32 v2 = (u32)f2bf(aS2[4]) | ((u32)f2bf(aS2[5]) << 16);
            u32 v3 = (u32)f2bf(aS2[6]) | ((u32)f2bf(aS2[7]) << 16);
            *(uint4*)(sI + s * WROW + bT) = make_uint4(v0, v1, v2, v3);
        }
    }
    __syncthreads();

#pragma unroll 1
    for (int m = 0; m < 2; ++m) {
        const int i = tid * 2 + m;
        const int t = t0 + i;
        const float hfn = (m == 0) ? hn0 : hn1;
        const float hfs = (m == 0) ? hs0 : hs1;

        float vs[SUB_NO], vn[SUB_NO];
#pragma unroll
        for (int c = 0; c < SUB_NO; ++c) { vs[c] = 0.f; vn[c] = 0.f; }
#pragma unroll
        for (int idx = SUB_NO - 1; idx >= 1; --idx) {
            float cs = 0.f, cn = 0.f;
#pragma unroll
            for (int c = 0; c < SUB_NO; ++c) {
                cs = fmaf(AS[idx][c], vs[c], cs);
                cn = fmaf(AN[idx][c], vn[c], cn);
            }
            float synS_v = bf2f(sI[idx * WROW + i]);
            float synN_v = bf2f(sE[idx * WROW + i]);
            vs[idx] = fast_tanh(synS_v + cs + ths[idx]);
            vn[idx] = fast_tanh(synN_v + cn + thn[idx]);
        }
        float cs0 = 0.f, cn0 = 0.f;
#pragma unroll
        for (int c = 0; c < SUB_NO; ++c) {
            cs0 = fmaf(AS[0][c], vs[c], cs0);
            cn0 = fmaf(AN[0][c], vn[c], cn0);
        }
        float s0  = fast_sigmoid(hfs + bf2f(sI[i]) + cs0 + ths[0]);
        float ns0 = fast_tanh(hfn + bf2f(sE[i]) + cn0 + thn[0]);

        if (t < T_DATA) {
            outV[t] = ns0 * wn20s + vos;
            outZ[t] = s0;
        }
    }
}

// ============================================================================
extern "C" void kernel_launch(void* const* d_in, const int* in_sizes, int n_in,
                              void* d_out, int out_size, void* d_ws, size_t ws_size,
                              hipStream_t stream)
{
    const float* Se    = (const float*)d_in[0];
    const float* Si    = (const float*)d_in[1];
    const float* Z     = (const float*)d_in[2];
    const int*   Cden  = (const int*)d_in[3];
    const float* Cse   = (const float*)d_in[4];
    const float* Csi   = (const float*)d_in[5];
    const float* Wns   = (const float*)d_in[6];
    const float* Tau   = (const float*)d_in[7];
    const float* Del   = (const float*)d_in[8];
    const float* Wsyns = (const float*)d_in[9];
    const float* WsubNS= (const float*)d_in[10];
    const float* WsubS = (const float*)d_in[11];
    const float* Vo    = (const float*)d_in[12];
    const float* ThNS  = (const float*)d_in[13];
    const float* ThS   = (const float*)d_in[14];
    const float* HwS   = (const float*)d_in[15];
    const float* HwNS  = (const float*)d_in[16];

    char* ws = (char*)d_ws;
    float4* k4    = (float4*)(ws + WS_K4);
    float2* hist2 = (float2*)(ws + WS_HIST2);
    int*    lists = (int*)(ws + WS_LISTS);

    float* outV = (float*)d_out;
    float* outZ = outV + T_DATA;
    float* outF = outV + 2 * T_DATA;

    k_setup<<<22, 256, 0, stream>>>(Wns, Tau, Del, Wsyns, HwS, HwNS, Cse, Csi,
                                    k4, hist2, lists, outF);

    if (ws_size >= (size_t)WS_NEED) {
        u16* synEb  = (u16*)(ws + WS_SYNE);
        u16* synIb  = (u16*)(ws + WS_SYNI);
        u16* synNSb = (u16*)(ws + WS_SNS);
        u16* synSb  = (u16*)(ws + WS_SS);
        float2* hfilt = (float2*)(ws + WS_HF);
        k_spikes<<<T_DATA / AR, 256, 0, stream>>>(Se, Si, lists, synEb, synIb);
        dim3 gc((T_DATA + TT - 1) / TT, 6);
        k_conv<<<gc, 256, 0, stream>>>(synEb, synIb, Z, k4, hist2,
                                       synNSb, synSb, hfilt);
        k_tree<<<(T_DATA + CT - 1) / CT, 256, 0, stream>>>(
            synNSb, synSb, hfilt, Cden, WsubNS, WsubS, Vo, ThNS, ThS,
            outV, outZ);
    } else {
        k_fused<<<(T_DATA + TT - 1) / TT, 256, 0, stream>>>(
            Se, Si, Z, k4, hist2, lists, Cden, WsubNS, WsubS, Vo, ThNS, ThS,
            outV, outZ);
    }
}